// Round 3
// baseline (206.142 us; speedup 1.0000x reference)
//
#include <hip/hip_runtime.h>
#include <math.h>

typedef float f32x4 __attribute__((ext_vector_type(4)));

// Problem constants: B=32, S=1024, H=768, F=128, P=256, NTYPE=7
#define B_    32
#define S_    1024
#define H_    768
#define F_    128
#define P_    256

// Output flat offsets (return order: msr, agg, msr_score, dim_score, key, pair, type)
#define OFF_MSR    0          // (32,128,2)
#define OFF_AGG    8192       // (32,128,9)
#define OFF_MSRS   45056      // (32,128,2)  msr_score (W_msrs)
#define OFF_DIM    53248      // (32,128,2)  dim_score (W_dim)
#define OFF_KEY    61440      // (32,128,2)
#define OFF_PAIR   69632      // (32,256,2)
#define OFF_TYPE   86016      // (32,128,7)

// ---------------- log-softmax epilogue --------------------------------------
template <int NC>
__device__ inline void write_logsoftmax(const float* __restrict__ acc,
                                        const float* __restrict__ bias,
                                        float* __restrict__ out) {
  float v[NC];
  float m = -1e30f;
#pragma unroll
  for (int c = 0; c < NC; ++c) { v[c] = acc[c] + bias[c]; m = fmaxf(m, v[c]); }
  float s = 0.f;
#pragma unroll
  for (int c = 0; c < NC; ++c) s += __expf(v[c] - m);
  const float lse = m + __logf(s);
#pragma unroll
  for (int c = 0; c < NC; ++c) out[c] = v[c] - lse;
}

__device__ inline void write_row(const float a[24], int r,
    const float* __restrict__ b_msr, const float* __restrict__ b_agg,
    const float* __restrict__ b_dim, const float* __restrict__ b_msrs,
    const float* __restrict__ b_key, const float* __restrict__ b_type,
    float* __restrict__ out)
{
  write_logsoftmax<2>(a + 0,  b_msr,  out + OFF_MSR  + r * 2);
  write_logsoftmax<9>(a + 2,  b_agg,  out + OFF_AGG  + r * 9);
  write_logsoftmax<2>(a + 11, b_dim,  out + OFF_DIM  + r * 2);
  write_logsoftmax<2>(a + 13, b_msrs, out + OFF_MSRS + r * 2);
  write_logsoftmax<2>(a + 15, b_key,  out + OFF_KEY  + r * 2);
  write_logsoftmax<7>(a + 17, b_type, out + OFF_TYPE + r * 7);
}

// Per-thread partial dot for one head with NC output cols, row-major W (H, NC).
// Thread t owns input rows 4t..4t+3 -> floats [4*NC*t, 4*NC*(t+1)), 16B-aligned
// for all NC in {2,7,9} (4*NC*4 bytes stride divisible by 16).
template <int NC, int OFFC>
__device__ inline void accum_head(const float* __restrict__ W, int tid,
                                  const float xv[4], float* __restrict__ part) {
  float wf[4 * NC];
  const float4* p = (const float4*)(W + 4 * NC * tid);
#pragma unroll
  for (int k = 0; k < NC; ++k) {
    const float4 v = p[k];
    wf[4 * k + 0] = v.x; wf[4 * k + 1] = v.y;
    wf[4 * k + 2] = v.z; wf[4 * k + 3] = v.w;
  }
#pragma unroll
  for (int j = 0; j < 4; ++j)
#pragma unroll
    for (int c = 0; c < NC; ++c)
      part[OFFC + c] = fmaf(xv[j], wf[NC * j + c], part[OFFC + c]);
}

// -------- Kernel 1: segment mean (inline bucketing) + ALL field heads -------
// grid = B*F blocks x 192 threads; thread t owns mean-row floats [4t,4t+3].
// part[] layout: 0-1 msr | 2-10 agg | 11-12 dim | 13-14 msrs | 15-16 key | 17-23 type
__global__ __launch_bounds__(192) void mean_heads_kernel(
    const float* __restrict__ x, const int* __restrict__ col_ids,
    const float* __restrict__ W_msr, const float* __restrict__ b_msr,
    const float* __restrict__ W_agg, const float* __restrict__ b_agg,
    const float* __restrict__ W_dim, const float* __restrict__ b_dim,
    const float* __restrict__ W_msrs, const float* __restrict__ b_msrs,
    const float* __restrict__ W_key, const float* __restrict__ b_key,
    const float* __restrict__ W_type, const float* __restrict__ b_type,
    float* __restrict__ fe, float* __restrict__ out)
{
  const int tid = threadIdx.x;
  const int b = blockIdx.x >> 7;       // F_ = 128
  const int f = blockIdx.x & (F_ - 1);
  __shared__ int slist[S_];
  __shared__ int nsh;
  __shared__ float red[3 * 24];
  if (tid == 0) nsh = 0;
  __syncthreads();
  const int target = f + 1;            // segment 0 (non-field) is dropped
  const int* ci = col_ids + b * S_;
  for (int s = tid; s < S_; s += 192)
    if (ci[s] == target) slist[atomicAdd(&nsh, 1)] = s;
  __syncthreads();
  const int cnt = nsh;
  const f32x4* xb = (const f32x4*)(x + (size_t)b * S_ * H_);

  // 4 independent accumulators -> 4 row-loads in flight per wave.
  f32x4 a0 = 0.f, a1 = 0.f, a2 = 0.f, a3 = 0.f;
  int i = 0;
  for (; i + 4 <= cnt; i += 4) {
    const int sA = slist[i];
    const int sB = slist[i + 1];
    const int sC = slist[i + 2];
    const int sD = slist[i + 3];
    const f32x4 vA = xb[(size_t)sA * 192 + tid];
    const f32x4 vB = xb[(size_t)sB * 192 + tid];
    const f32x4 vC = xb[(size_t)sC * 192 + tid];
    const f32x4 vD = xb[(size_t)sD * 192 + tid];
    a0 += vA; a1 += vB; a2 += vC; a3 += vD;
  }
  for (; i < cnt; ++i) a0 += xb[(size_t)slist[i] * 192 + tid];
  f32x4 acc = (a0 + a1) + (a2 + a3);
  const float scale = 1.0f / (float)(cnt > 0 ? cnt : 1);
  acc.x *= scale; acc.y *= scale; acc.z *= scale; acc.w *= scale;
  ((f32x4*)(fe + ((size_t)(b * F_ + f)) * H_))[tid] = acc;  // for pair kernel

  // ---- field heads, fused: per-thread partials over its 4 h-elements ----
  const float xv[4] = {acc.x, acc.y, acc.z, acc.w};
  float part[24];
#pragma unroll
  for (int c = 0; c < 24; ++c) part[c] = 0.f;
  accum_head<2, 0 >(W_msr,  tid, xv, part);
  accum_head<9, 2 >(W_agg,  tid, xv, part);
  accum_head<2, 11>(W_dim,  tid, xv, part);
  accum_head<2, 13>(W_msrs, tid, xv, part);
  accum_head<2, 15>(W_key,  tid, xv, part);
  accum_head<7, 17>(W_type, tid, xv, part);

  // wave butterfly (all lanes end with wave sum), then cross-wave via LDS
#pragma unroll
  for (int m = 1; m < 64; m <<= 1)
#pragma unroll
    for (int c = 0; c < 24; ++c) part[c] += __shfl_xor(part[c], m, 64);

  const int lane = tid & 63;
  const int wave = tid >> 6;
  if (lane == 0) {
#pragma unroll
    for (int c = 0; c < 24; ++c) red[wave * 24 + c] = part[c];
  }
  __syncthreads();
  if (tid == 0) {
    float a[24];
#pragma unroll
    for (int c = 0; c < 24; ++c) a[c] = red[c] + red[24 + c] + red[48 + c];
    write_row(a, b * F_ + f, b_msr, b_agg, b_dim, b_msrs, b_key, b_type, out);
  }
}

// -------- Kernel 2: pair head only -----------------------------------------
// 512 blocks x 512 threads; 8 waves/block, 2 rows/wave -> 8192 rows.
// W_pair (1536,2) read directly: rows e..e+3 -> 8 contiguous floats at 32e B.
__global__ __launch_bounds__(512) void pair_kernel(
    const float* __restrict__ fe, const int* __restrict__ pair_idx,
    const float* __restrict__ W_pair, const float* __restrict__ b_pair,
    float* __restrict__ out)
{
  const int tid  = threadIdx.x;
  const int lane = tid & 63;
  const int wave = tid >> 6;
  const int r0 = (blockIdx.x * 8 + wave) * 2;  // rows in [0,8192)
  float acc[2][2] = {{0.f, 0.f}, {0.f, 0.f}};
#pragma unroll
  for (int rr = 0; rr < 2; ++rr) {
    const int r = r0 + rr;
    const int b = r >> 8;
    const int i1 = pair_idx[r * 2 + 0];
    const int i2 = pair_idx[r * 2 + 1];
    const float4* q1 = (const float4*)(fe + ((size_t)(b * F_ + i1)) * H_);
    const float4* q2 = (const float4*)(fe + ((size_t)(b * F_ + i2)) * H_);
#pragma unroll
    for (int j = 0; j < 6; ++j) {
      const int e4 = lane + 64 * (j < 3 ? j : j - 3);     // float4 idx in row
      const float4 xv = (j < 3) ? q1[e4] : q2[e4];
      const int e = (j < 3 ? 0 : 768) + e4 * 4;           // elem idx in [0,1536)
      const float4* wp = (const float4*)(W_pair + e * 2);
      const float4 wA = wp[0];  // {W[e][0],W[e][1],W[e+1][0],W[e+1][1]}
      const float4 wB = wp[1];  // {W[e+2][0],W[e+2][1],W[e+3][0],W[e+3][1]}
      acc[rr][0] = fmaf(xv.x, wA.x, acc[rr][0]);
      acc[rr][1] = fmaf(xv.x, wA.y, acc[rr][1]);
      acc[rr][0] = fmaf(xv.y, wA.z, acc[rr][0]);
      acc[rr][1] = fmaf(xv.y, wA.w, acc[rr][1]);
      acc[rr][0] = fmaf(xv.z, wB.x, acc[rr][0]);
      acc[rr][1] = fmaf(xv.z, wB.y, acc[rr][1]);
      acc[rr][0] = fmaf(xv.w, wB.z, acc[rr][0]);
      acc[rr][1] = fmaf(xv.w, wB.w, acc[rr][1]);
    }
  }
#pragma unroll
  for (int m = 1; m < 64; m <<= 1)
#pragma unroll
    for (int rr = 0; rr < 2; ++rr) {
      acc[rr][0] += __shfl_xor(acc[rr][0], m, 64);
      acc[rr][1] += __shfl_xor(acc[rr][1], m, 64);
    }
  if (lane == 0) write_logsoftmax<2>(acc[0], b_pair, out + OFF_PAIR + r0 * 2);
  if (lane == 1) write_logsoftmax<2>(acc[1], b_pair, out + OFF_PAIR + (r0 + 1) * 2);
}

// ---------------------------------------------------------------------------
extern "C" void kernel_launch(void* const* d_in, const int* in_sizes, int n_in,
                              void* d_out, int out_size, void* d_ws, size_t ws_size,
                              hipStream_t stream) {
  const float* x        = (const float*)d_in[0];   // (32,1024,768) f32
  const int*   col_ids  = (const int*)d_in[1];     // (32,1024) i32
  const int*   pair_idx = (const int*)d_in[2];     // (32,256,2) i32
  const float* W_msr  = (const float*)d_in[4];  const float* b_msr  = (const float*)d_in[5];
  const float* W_agg  = (const float*)d_in[6];  const float* b_agg  = (const float*)d_in[7];
  const float* W_dim  = (const float*)d_in[8];  const float* b_dim  = (const float*)d_in[9];
  const float* W_msrs = (const float*)d_in[10]; const float* b_msrs = (const float*)d_in[11];
  const float* W_key  = (const float*)d_in[12]; const float* b_key  = (const float*)d_in[13];
  const float* W_pair = (const float*)d_in[14]; const float* b_pair = (const float*)d_in[15];
  const float* W_type = (const float*)d_in[16]; const float* b_type = (const float*)d_in[17];
  float* out = (float*)d_out;

  // ws layout: fe only (B*F*H floats, every byte rewritten each call)
  float* fe = (float*)d_ws;

  mean_heads_kernel<<<B_ * F_, 192, 0, stream>>>(
      x, col_ids,
      W_msr, b_msr, W_agg, b_agg, W_dim, b_dim,
      W_msrs, b_msrs, W_key, b_key, W_type, b_type,
      fe, out);
  pair_kernel<<<512, 512, 0, stream>>>(fe, pair_idx, W_pair, b_pair, out);
}